// Round 5
// baseline (39.874 us; speedup 1.0000x reference)
//
#include <hip/hip_runtime.h>

#define BATCH 16384
#define NU 1000000
#define TBR 64           // rows per block
#define MT 512           // threads, 8 waves

typedef __attribute__((ext_vector_type(8))) short short8;
typedef __attribute__((ext_vector_type(4))) short short4v;
typedef __attribute__((ext_vector_type(4))) float f32x4;

__device__ __forceinline__ unsigned short f32_bf16(float f) {
    unsigned int u = __float_as_uint(f);
    u += 0x7FFF + ((u >> 16) & 1);   // RTNE
    return (unsigned short)(u >> 16);
}
__device__ __forceinline__ float bf16_f32(unsigned short h) {
    return __uint_as_float(((unsigned int)h) << 16);
}

// XOR swizzle: 16B granule spread by row (bank-conflict-free ds_read_b128).
__device__ __forceinline__ int swz(int row, int byteInRow, int rowStrideB) {
    return row * rowStrideB + (byteInRow ^ ((row & 7) << 4));
}

__device__ __forceinline__ short8 cvt8(float4 a, float4 b) {
    short8 s;
    s[0] = (short)f32_bf16(a.x); s[1] = (short)f32_bf16(a.y);
    s[2] = (short)f32_bf16(a.z); s[3] = (short)f32_bf16(a.w);
    s[4] = (short)f32_bf16(b.x); s[5] = (short)f32_bf16(b.y);
    s[6] = (short)f32_bf16(b.z); s[7] = (short)f32_bf16(b.w);
    return s;
}

// Build a bf16 B-fragment from row-major fp32 W[k][n]: frag[i] = bf16(W[kb+i][col]).
// K,N are call-site literals; the k<K guard folds away except for W0's tail.
__device__ __forceinline__ short8 mk_frag(const float* __restrict__ W, int N, int K,
                                          int col, int kb) {
    short8 f;
    #pragma unroll
    for (int i = 0; i < 8; ++i) {
        int k = kb + i;
        float v = (k < K) ? W[(size_t)k * N + col] : 0.f;
        f[i] = (short)f32_bf16(v);
    }
    return f;
}

// ---- Single fused kernel: 256 blocks x 512 thr, 64 rows/block ----
__global__ __launch_bounds__(MT, 1) void wd_mfma(
        const int* __restrict__ user, const int* __restrict__ item,
        const float* __restrict__ genre, const float* __restrict__ tag,
        const float* __restrict__ wide_W, const float* __restrict__ wide_b,
        const float* __restrict__ user_emb, const float* __restrict__ item_emb,
        const float* __restrict__ W0, const float* __restrict__ b0,
        const float* __restrict__ W1, const float* __restrict__ b1,
        const float* __restrict__ W2, const float* __restrict__ b2,
        const float* __restrict__ fW, const float* __restrict__ fb,
        float* __restrict__ out)
{
    __shared__ unsigned short sX[TBR * 256];   // x tile bf16 (swizzled, 512B rows)
    __shared__ unsigned short sH0[TBR * 256];  // h0 bf16 (swizzled, 512B rows)
    __shared__ unsigned short sH1[TBR * 128];  // h1 bf16 (swizzled, 256B rows)
    __shared__ unsigned short sH2[TBR * 72];   // h2 bf16 (stride 72)
    __shared__ unsigned short sWide[TBR * 72]; // wide bf16 (stride 72)
    __shared__ float sFW[640];                 // fW fp32

    const int tid = threadIdx.x;
    const int row0 = blockIdx.x * TBR;

    const int wid = tid >> 6;
    const int lane = tid & 63;
    const int lr = lane & 15;     // row/col within 16-tile
    const int lh = lane >> 4;     // k-chunk 0..3

    // ========== 1) Issue ALL gather loads (HBM, long latency) into registers ==========
    float4 xa[4], xb[4];
    #pragma unroll
    for (int it = 0; it < 4; ++it) {
        int q = tid + it * MT;
        int r = q >> 5, j = q & 31;
        int grow = row0 + r;
        float4 va = make_float4(0.f, 0.f, 0.f, 0.f);
        float4 vb = va;
        if (j < 8) {
            const float4* p = (const float4*)(user_emb + (size_t)user[grow] * 64);
            va = p[j * 2]; vb = p[j * 2 + 1];
        } else if (j < 16) {
            const float4* p = (const float4*)(item_emb + (size_t)item[grow] * 64);
            va = p[(j - 8) * 2]; vb = p[(j - 8) * 2 + 1];
        } else if (j == 16) {
            const float4* p = (const float4*)(genre + (size_t)grow * 20);
            va = p[0]; vb = p[1];
        } else if (j == 17) {
            const float4* p = (const float4*)(genre + (size_t)grow * 20);
            va = p[2]; vb = p[3];
        } else if (j == 18) {
            va = *(const float4*)(genre + (size_t)grow * 20 + 16);
            vb = *(const float4*)(tag + (size_t)grow * 100);
        } else if (j < 31) {
            const float4* p = (const float4*)(tag + (size_t)grow * 100 + 4);
            int jj = j - 19;
            va = p[jj * 2]; vb = p[jj * 2 + 1];
        } // j == 31: zero pad (k 248..255)
        xa[it] = va; xb[it] = vb;
    }
    float4 wa[2], wb[2];
    {
        int j = tid & 15;
        #pragma unroll
        for (int it = 0; it < 2; ++it) {
            int q = tid + it * MT;
            int r = q >> 4;
            int grow = row0 + r;
            wa[it] = ((const float4*)(wide_W + (size_t)user[grow] * 64))[j];
            wb[it] = ((const float4*)(wide_W + (size_t)(NU + item[grow]) * 64))[j];
        }
    }
    float4 wc = ((const float4*)wide_b)[tid & 15];
    float4 fwv = make_float4(0.f, 0.f, 0.f, 0.f);
    if (tid < 160) fwv = ((const float4*)fW)[tid];

    // ========== 2) Build weight B-fragments from fp32 (L2/L3) — overlaps gather latency ==========
    const int cb0 = wid * 32;     // L0 col strip
    const int cb1 = wid * 16;     // L1 col strip
    const int cb2 = (wid & 3) * 16;
    short8 B0[2][8];
    #pragma unroll
    for (int t = 0; t < 2; ++t)
        #pragma unroll
        for (int kc = 0; kc < 8; ++kc)
            B0[t][kc] = mk_frag(W0, 256, 248, cb0 + t * 16 + lr, kc * 32 + lh * 8);
    short8 B1[8];
    #pragma unroll
    for (int kc = 0; kc < 8; ++kc)
        B1[kc] = mk_frag(W1, 128, 256, cb1 + lr, kc * 32 + lh * 8);
    short8 B2f[4];
    #pragma unroll
    for (int kc = 0; kc < 4; ++kc)
        B2f[kc] = mk_frag(W2, 64, 128, cb2 + lr, kc * 32 + lh * 8);

    float rb0[2];
    rb0[0] = b0[cb0 + lr]; rb0[1] = b0[cb0 + 16 + lr];
    float rb1 = b1[cb1 + lr];
    float rb2 = b2[cb2 + lr];

    // ========== 3) Write staged gathers to LDS ==========
    #pragma unroll
    for (int it = 0; it < 4; ++it) {
        int q = tid + it * MT;
        int r = q >> 5, j = q & 31;
        *(short8*)((char*)sX + swz(r, j * 16, 512)) = cvt8(xa[it], xb[it]);
    }
    #pragma unroll
    for (int it = 0; it < 2; ++it) {
        int q = tid + it * MT;
        int r = q >> 4, j = q & 15;
        short4v o;
        o[0] = (short)f32_bf16(wa[it].x + wb[it].x + wc.x);
        o[1] = (short)f32_bf16(wa[it].y + wb[it].y + wc.y);
        o[2] = (short)f32_bf16(wa[it].z + wb[it].z + wc.z);
        o[3] = (short)f32_bf16(wa[it].w + wb[it].w + wc.w);
        *(short4v*)(sWide + r * 72 + j * 4) = o;
    }
    if (tid < 160) ((float4*)sFW)[tid] = fwv;
    __syncthreads();

    // ---- Layer 0: x[64][256] @ W0 -> h0[64][256] (wave = 32-col strip) ----
    {
        f32x4 acc[4][2];
        #pragma unroll
        for (int rt = 0; rt < 4; ++rt)
            #pragma unroll
            for (int t = 0; t < 2; ++t) acc[rt][t] = (f32x4)(0.f);

        #pragma unroll
        for (int kc = 0; kc < 8; ++kc) {
            const int kb = kc * 32 + lh * 8;
            short8 a[4];
            #pragma unroll
            for (int rt = 0; rt < 4; ++rt)
                a[rt] = *(const short8*)((const char*)sX + swz(rt * 16 + lr, kb * 2, 512));
            #pragma unroll
            for (int t = 0; t < 2; ++t)
                #pragma unroll
                for (int rt = 0; rt < 4; ++rt)
                    acc[rt][t] = __builtin_amdgcn_mfma_f32_16x16x32_bf16(a[rt], B0[t][kc], acc[rt][t], 0, 0, 0);
        }
        #pragma unroll
        for (int t = 0; t < 2; ++t) {
            #pragma unroll
            for (int rt = 0; rt < 4; ++rt)
                #pragma unroll
                for (int jj = 0; jj < 4; ++jj) {
                    int row = rt * 16 + lh * 4 + jj;
                    float v = fmaxf(acc[rt][t][jj] + rb0[t], 0.f);
                    *(unsigned short*)((char*)sH0 + swz(row, (cb0 + t * 16 + lr) * 2, 512)) = f32_bf16(v);
                }
        }
        __syncthreads();
    }

    // ---- Layer 1: h0[64][256] @ W1 -> h1[64][128] (wave = 16-col strip) ----
    {
        f32x4 acc[4];
        #pragma unroll
        for (int rt = 0; rt < 4; ++rt) acc[rt] = (f32x4)(0.f);

        #pragma unroll
        for (int kc = 0; kc < 8; ++kc) {
            const int kb = kc * 32 + lh * 8;
            short8 a[4];
            #pragma unroll
            for (int rt = 0; rt < 4; ++rt)
                a[rt] = *(const short8*)((const char*)sH0 + swz(rt * 16 + lr, kb * 2, 512));
            #pragma unroll
            for (int rt = 0; rt < 4; ++rt)
                acc[rt] = __builtin_amdgcn_mfma_f32_16x16x32_bf16(a[rt], B1[kc], acc[rt], 0, 0, 0);
        }
        #pragma unroll
        for (int rt = 0; rt < 4; ++rt)
            #pragma unroll
            for (int jj = 0; jj < 4; ++jj) {
                int row = rt * 16 + lh * 4 + jj;
                float v = fmaxf(acc[rt][jj] + rb1, 0.f);
                *(unsigned short*)((char*)sH1 + swz(row, (cb1 + lr) * 2, 256)) = f32_bf16(v);
            }
        __syncthreads();
    }

    // ---- Layer 2: h1[64][128] @ W2 -> h2[64][64] bf16 ----
    {
        const int rtb = (wid >> 2) * 2;   // 0 or 2
        f32x4 acc[2];
        acc[0] = (f32x4)(0.f); acc[1] = (f32x4)(0.f);

        #pragma unroll
        for (int kc = 0; kc < 4; ++kc) {
            const int kb = kc * 32 + lh * 8;
            #pragma unroll
            for (int rr = 0; rr < 2; ++rr) {
                short8 a = *(const short8*)((const char*)sH1 + swz((rtb + rr) * 16 + lr, kb * 2, 256));
                acc[rr] = __builtin_amdgcn_mfma_f32_16x16x32_bf16(a, B2f[kc], acc[rr], 0, 0, 0);
            }
        }
        #pragma unroll
        for (int rr = 0; rr < 2; ++rr)
            #pragma unroll
            for (int jj = 0; jj < 4; ++jj) {
                int row = (rtb + rr) * 16 + lh * 4 + jj;
                sH2[row * 72 + cb2 + lr] = f32_bf16(fmaxf(acc[rr][jj] + rb2, 0.f));
            }
        __syncthreads();
    }

    // ---- Final: [h2 | wide] @ fW + fb (fp32 VALU, LDS reads) ----
    if (tid < TBR * 5) {
        int r = tid / 5, c = tid - r * 5;
        float acc = fb[c];
        #pragma unroll
        for (int kq = 0; kq < 8; ++kq) {
            short8 h = *(const short8*)(sH2 + r * 72 + kq * 8);
            #pragma unroll
            for (int i = 0; i < 8; ++i)
                acc = fmaf(bf16_f32((unsigned short)h[i]), sFW[(kq * 8 + i) * 5 + c], acc);
        }
        #pragma unroll
        for (int kq = 0; kq < 8; ++kq) {
            short8 h = *(const short8*)(sWide + r * 72 + kq * 8);
            #pragma unroll
            for (int i = 0; i < 8; ++i)
                acc = fmaf(bf16_f32((unsigned short)h[i]), sFW[(64 + kq * 8 + i) * 5 + c], acc);
        }
        out[(size_t)(row0 + r) * 5 + c] = acc;
    }
}

extern "C" void kernel_launch(void* const* d_in, const int* in_sizes, int n_in,
                              void* d_out, int out_size, void* d_ws, size_t ws_size,
                              hipStream_t stream) {
    const int* user = (const int*)d_in[0];
    const int* item = (const int*)d_in[1];
    const float* genre = (const float*)d_in[2];
    const float* tag = (const float*)d_in[3];
    const float* wide_W = (const float*)d_in[4];
    const float* wide_b = (const float*)d_in[5];
    const float* user_emb = (const float*)d_in[6];
    const float* item_emb = (const float*)d_in[7];
    const float* W0 = (const float*)d_in[8];
    const float* b0 = (const float*)d_in[9];
    const float* W1 = (const float*)d_in[10];
    const float* b1 = (const float*)d_in[11];
    const float* W2 = (const float*)d_in[12];
    const float* b2 = (const float*)d_in[13];
    const float* fW = (const float*)d_in[14];
    const float* fb = (const float*)d_in[15];
    float* out = (float*)d_out;

    hipLaunchKernelGGL(wd_mfma, dim3(BATCH / TBR), dim3(MT), 0, stream,
                       user, item, genre, tag, wide_W, wide_b, user_emb, item_emb,
                       W0, b0, W1, b1, W2, b2, fW, fb, out);
}

// Round 6
// 30.859 us; speedup vs baseline: 1.2922x; 1.2922x over previous
//
#include <hip/hip_runtime.h>

#define BATCH 16384
#define NU 1000000
#define TBR 64           // rows per block (mfma kernel)
#define MT 512           // threads (mfma kernel), 8 waves
#define WSOFF0 0         // W0t [256][256] bf16
#define WSOFF1 65536     // W1t [128][256] bf16
#define WSOFF2 98304     // W2t [64][128]  bf16
#define WSREQ  212992    // bytes of ws needed

typedef __attribute__((ext_vector_type(8))) short short8;
typedef __attribute__((ext_vector_type(4))) short short4v;
typedef __attribute__((ext_vector_type(4))) float f32x4;

__device__ __forceinline__ unsigned short f32_bf16(float f) {
    unsigned int u = __float_as_uint(f);
    u += 0x7FFF + ((u >> 16) & 1);   // RTNE
    return (unsigned short)(u >> 16);
}
__device__ __forceinline__ float bf16_f32(unsigned short h) {
    return __uint_as_float(((unsigned int)h) << 16);
}

// XOR swizzle: 16B granule spread by row (bank-conflict-free ds_read_b128).
__device__ __forceinline__ int swz(int row, int byteInRow, int rowStrideB) {
    return row * rowStrideB + (byteInRow ^ ((row & 7) << 4));
}

__device__ __forceinline__ short8 cvt8(float4 a, float4 b) {
    short8 s;
    s[0] = (short)f32_bf16(a.x); s[1] = (short)f32_bf16(a.y);
    s[2] = (short)f32_bf16(a.z); s[3] = (short)f32_bf16(a.w);
    s[4] = (short)f32_bf16(b.x); s[5] = (short)f32_bf16(b.y);
    s[6] = (short)f32_bf16(b.z); s[7] = (short)f32_bf16(b.w);
    return s;
}

// ---- Pre-pass: transpose + bf16-convert weights into ws (Wt[n][k]) ----
// 52 blocks, each a 32(k) x 64(n) tile: 2x wider than the 26-block version.
__global__ void prep_weights(const float* __restrict__ W0, const float* __restrict__ W1,
                             const float* __restrict__ W2, unsigned short* __restrict__ ws)
{
    __shared__ float t[32 * 65];
    int b = blockIdx.x;
    const float* src; unsigned short* dst; int K, N, K2, k0, n0;
    if (b < 32)      { src = W0; dst = ws + WSOFF0; K = 248; N = 256; K2 = 256; k0 = (b >> 2) * 32; n0 = (b & 3) * 64; }
    else if (b < 48) { int i = b - 32; src = W1; dst = ws + WSOFF1; K = 256; N = 128; K2 = 256; k0 = (i >> 1) * 32; n0 = (i & 1) * 64; }
    else             { int i = b - 48; src = W2; dst = ws + WSOFF2; K = 128; N = 64;  K2 = 128; k0 = i * 32; n0 = 0; }

    int tid = threadIdx.x;
    for (int q = tid; q < 32 * 16; q += 256) {
        int k = q >> 4, nq = q & 15;
        float4 v = make_float4(0.f, 0.f, 0.f, 0.f);
        if (k0 + k < K) v = *(const float4*)(src + (size_t)(k0 + k) * N + n0 + nq * 4);
        t[k * 65 + nq * 4 + 0] = v.x;
        t[k * 65 + nq * 4 + 1] = v.y;
        t[k * 65 + nq * 4 + 2] = v.z;
        t[k * 65 + nq * 4 + 3] = v.w;
    }
    __syncthreads();
    // 64 n-cols x 4 k-groups of 8 = 256 tasks, one per thread
    {
        int q = tid;
        int n = q >> 2, kg = q & 3;
        short8 o;
        #pragma unroll
        for (int i = 0; i < 8; ++i) o[i] = (short)f32_bf16(t[(kg * 8 + i) * 65 + n]);
        *(short8*)(dst + (size_t)(n0 + n) * K2 + k0 + kg * 8) = o;
    }
}

// ---- Main fused MFMA kernel: 256 blocks x 512 thr, 64 rows/block ----
__global__ __launch_bounds__(MT, 1) void wd_mfma(
        const int* __restrict__ user, const int* __restrict__ item,
        const float* __restrict__ genre, const float* __restrict__ tag,
        const float* __restrict__ wide_W, const float* __restrict__ wide_b,
        const float* __restrict__ user_emb, const float* __restrict__ item_emb,
        const float* __restrict__ b0, const float* __restrict__ b1,
        const float* __restrict__ b2,
        const float* __restrict__ fW, const float* __restrict__ fb,
        const unsigned short* __restrict__ ws, float* __restrict__ out)
{
    __shared__ unsigned short sX[TBR * 256];   // x tile bf16 (swizzled, 512B rows)
    __shared__ unsigned short sH0[TBR * 256];  // h0 bf16 (swizzled, 512B rows)
    __shared__ unsigned short sH1[TBR * 128];  // h1 bf16 (swizzled, 256B rows)
    __shared__ unsigned short sH2[TBR * 72];   // h2 bf16 (stride 72)
    __shared__ unsigned short sWide[TBR * 72]; // wide bf16 (stride 72)
    __shared__ float sFW[640];                 // fW fp32

    const int tid = threadIdx.x;
    const int row0 = blockIdx.x * TBR;
    const unsigned short* w0t = ws + WSOFF0;
    const unsigned short* w1t = ws + WSOFF1;
    const unsigned short* w2t = ws + WSOFF2;

    const int wid = tid >> 6;
    const int lane = tid & 63;
    const int lr = lane & 15;     // row/col within 16-tile
    const int lh = lane >> 4;     // k-chunk 0..3

    // ---- Prefetch ALL weight B-fragments + biases into registers (pre-barrier) ----
    const int cb0 = wid * 32;     // L0 col strip
    const int cb1 = wid * 16;     // L1 col strip
    const int cb2 = (wid & 3) * 16;
    short8 B0[2][8];
    #pragma unroll
    for (int t = 0; t < 2; ++t)
        #pragma unroll
        for (int kc = 0; kc < 8; ++kc)
            B0[t][kc] = *(const short8*)(w0t + (size_t)(cb0 + t * 16 + lr) * 256 + kc * 32 + lh * 8);
    short8 B1[8];
    #pragma unroll
    for (int kc = 0; kc < 8; ++kc)
        B1[kc] = *(const short8*)(w1t + (size_t)(cb1 + lr) * 256 + kc * 32 + lh * 8);
    short8 B2f[4];
    #pragma unroll
    for (int kc = 0; kc < 4; ++kc)
        B2f[kc] = *(const short8*)(w2t + (size_t)(cb2 + lr) * 128 + kc * 32 + lh * 8);
    float rb0[2];
    rb0[0] = b0[cb0 + lr]; rb0[1] = b0[cb0 + 16 + lr];
    float rb1 = b1[cb1 + lr];
    float rb2 = b2[cb2 + lr];

    // ---- Stage x (bf16, swizzled) + wide path together: all gathers overlap ----
    #pragma unroll
    for (int it = 0; it < 6; ++it) {
        int q = tid + it * MT;
        if (it < 4) {
            int r = q >> 5, j = q & 31;
            int grow = row0 + r;
            float4 va = make_float4(0.f, 0.f, 0.f, 0.f);
            float4 vb = va;
            if (j < 8) {
                const float4* p = (const float4*)(user_emb + (size_t)user[grow] * 64);
                va = p[j * 2]; vb = p[j * 2 + 1];
            } else if (j < 16) {
                const float4* p = (const float4*)(item_emb + (size_t)item[grow] * 64);
                va = p[(j - 8) * 2]; vb = p[(j - 8) * 2 + 1];
            } else if (j == 16) {
                const float4* p = (const float4*)(genre + (size_t)grow * 20);
                va = p[0]; vb = p[1];
            } else if (j == 17) {
                const float4* p = (const float4*)(genre + (size_t)grow * 20);
                va = p[2]; vb = p[3];
            } else if (j == 18) {
                va = *(const float4*)(genre + (size_t)grow * 20 + 16);
                vb = *(const float4*)(tag + (size_t)grow * 100);
            } else if (j < 31) {
                const float4* p = (const float4*)(tag + (size_t)grow * 100 + 4);
                int jj = j - 19;
                va = p[jj * 2]; vb = p[jj * 2 + 1];
            } // j == 31: zero pad (k 248..255)
            *(short8*)((char*)sX + swz(r, j * 16, 512)) = cvt8(va, vb);
        } else {
            int p = q - 4 * MT;
            int r = p >> 4, j = p & 15;
            int grow = row0 + r;
            float4 a = ((const float4*)(wide_W + (size_t)user[grow] * 64))[j];
            float4 b = ((const float4*)(wide_W + (size_t)(NU + item[grow]) * 64))[j];
            float4 c = ((const float4*)wide_b)[j];
            short4v o;
            o[0] = (short)f32_bf16(a.x + b.x + c.x);
            o[1] = (short)f32_bf16(a.y + b.y + c.y);
            o[2] = (short)f32_bf16(a.z + b.z + c.z);
            o[3] = (short)f32_bf16(a.w + b.w + c.w);
            *(short4v*)(sWide + r * 72 + j * 4) = o;
        }
    }
    if (tid < 160) {
        ((float4*)sFW)[tid] = ((const float4*)fW)[tid];
    }
    __syncthreads();

    // ---- Layer 0: x[64][256] @ W0t -> h0[64][256] (wave = 32-col strip) ----
    {
        f32x4 acc[4][2];
        #pragma unroll
        for (int rt = 0; rt < 4; ++rt)
            #pragma unroll
            for (int t = 0; t < 2; ++t) acc[rt][t] = (f32x4)(0.f);

        #pragma unroll
        for (int kc = 0; kc < 8; ++kc) {
            const int kb = kc * 32 + lh * 8;
            short8 a[4];
            #pragma unroll
            for (int rt = 0; rt < 4; ++rt)
                a[rt] = *(const short8*)((const char*)sX + swz(rt * 16 + lr, kb * 2, 512));
            #pragma unroll
            for (int t = 0; t < 2; ++t)
                #pragma unroll
                for (int rt = 0; rt < 4; ++rt)
                    acc[rt][t] = __builtin_amdgcn_mfma_f32_16x16x32_bf16(a[rt], B0[t][kc], acc[rt][t], 0, 0, 0);
        }
        #pragma unroll
        for (int t = 0; t < 2; ++t) {
            #pragma unroll
            for (int rt = 0; rt < 4; ++rt)
                #pragma unroll
                for (int jj = 0; jj < 4; ++jj) {
                    int row = rt * 16 + lh * 4 + jj;
                    float v = fmaxf(acc[rt][t][jj] + rb0[t], 0.f);
                    *(unsigned short*)((char*)sH0 + swz(row, (cb0 + t * 16 + lr) * 2, 512)) = f32_bf16(v);
                }
        }
        __syncthreads();
    }

    // ---- Layer 1: h0[64][256] @ W1t -> h1[64][128] (wave = 16-col strip) ----
    {
        f32x4 acc[4];
        #pragma unroll
        for (int rt = 0; rt < 4; ++rt) acc[rt] = (f32x4)(0.f);

        #pragma unroll
        for (int kc = 0; kc < 8; ++kc) {
            const int kb = kc * 32 + lh * 8;
            short8 a[4];
            #pragma unroll
            for (int rt = 0; rt < 4; ++rt)
                a[rt] = *(const short8*)((const char*)sH0 + swz(rt * 16 + lr, kb * 2, 512));
            #pragma unroll
            for (int rt = 0; rt < 4; ++rt)
                acc[rt] = __builtin_amdgcn_mfma_f32_16x16x32_bf16(a[rt], B1[kc], acc[rt], 0, 0, 0);
        }
        #pragma unroll
        for (int rt = 0; rt < 4; ++rt)
            #pragma unroll
            for (int jj = 0; jj < 4; ++jj) {
                int row = rt * 16 + lh * 4 + jj;
                float v = fmaxf(acc[rt][jj] + rb1, 0.f);
                *(unsigned short*)((char*)sH1 + swz(row, (cb1 + lr) * 2, 256)) = f32_bf16(v);
            }
        __syncthreads();
    }

    // ---- Layer 2: h1[64][128] @ W2t -> h2[64][64] bf16 (B2 pre-fetched) ----
    {
        const int rtb = (wid >> 2) * 2;   // 0 or 2
        f32x4 acc[2];
        acc[0] = (f32x4)(0.f); acc[1] = (f32x4)(0.f);

        #pragma unroll
        for (int kc = 0; kc < 4; ++kc) {
            const int kb = kc * 32 + lh * 8;
            #pragma unroll
            for (int rr = 0; rr < 2; ++rr) {
                short8 a = *(const short8*)((const char*)sH1 + swz((rtb + rr) * 16 + lr, kb * 2, 256));
                acc[rr] = __builtin_amdgcn_mfma_f32_16x16x32_bf16(a, B2f[kc], acc[rr], 0, 0, 0);
            }
        }
        #pragma unroll
        for (int rr = 0; rr < 2; ++rr)
            #pragma unroll
            for (int jj = 0; jj < 4; ++jj) {
                int row = (rtb + rr) * 16 + lh * 4 + jj;
                sH2[row * 72 + cb2 + lr] = f32_bf16(fmaxf(acc[rr][jj] + rb2, 0.f));
            }
        __syncthreads();
    }

    // ---- Final: [h2 | wide] @ fW + fb (fp32 VALU, LDS reads) ----
    if (tid < TBR * 5) {
        int r = tid / 5, c = tid - r * 5;
        float acc = fb[c];
        #pragma unroll
        for (int kq = 0; kq < 8; ++kq) {
            short8 h = *(const short8*)(sH2 + r * 72 + kq * 8);
            #pragma unroll
            for (int i = 0; i < 8; ++i)
                acc = fmaf(bf16_f32((unsigned short)h[i]), sFW[(kq * 8 + i) * 5 + c], acc);
        }
        #pragma unroll
        for (int kq = 0; kq < 8; ++kq) {
            short8 h = *(const short8*)(sWide + r * 72 + kq * 8);
            #pragma unroll
            for (int i = 0; i < 8; ++i)
                acc = fmaf(bf16_f32((unsigned short)h[i]), sFW[(64 + kq * 8 + i) * 5 + c], acc);
        }
        out[(size_t)(row0 + r) * 5 + c] = acc;
    }
}

// ================= fp32 fallback (used if ws too small) =================
#define NTHR 256
#define TB 32

__device__ __forceinline__ void fma4(float4& a, float s, const float4& w) {
    a.x = fmaf(s, w.x, a.x); a.y = fmaf(s, w.y, a.y);
    a.z = fmaf(s, w.z, a.z); a.w = fmaf(s, w.w, a.w);
}
__device__ __forceinline__ float4 add4(const float4& a, const float4& b) {
    return make_float4(a.x + b.x, a.y + b.y, a.z + b.z, a.w + b.w);
}
__device__ __forceinline__ float4 relu4(const float4& a) {
    return make_float4(fmaxf(a.x, 0.f), fmaxf(a.y, 0.f), fmaxf(a.z, 0.f), fmaxf(a.w, 0.f));
}

__global__ void wd_fused(const int* __restrict__ user, const int* __restrict__ item,
                         const float* __restrict__ genre, const float* __restrict__ tag,
                         const float* __restrict__ wide_W, const float* __restrict__ wide_b,
                         const float* __restrict__ user_emb, const float* __restrict__ item_emb,
                         const float* __restrict__ W0, const float* __restrict__ b0,
                         const float* __restrict__ W1, const float* __restrict__ b1,
                         const float* __restrict__ W2, const float* __restrict__ b2,
                         const float* __restrict__ fW, const float* __restrict__ fb,
                         float* __restrict__ out)
{
    __shared__ float sA[TB * 248];
    __shared__ float sB[TB * 256];
    __shared__ float sC[TB * 64];

    const int tid = threadIdx.x;
    const int row0 = blockIdx.x * TB;

    for (int q = tid; q < TB * 62; q += NTHR) {
        int r = q / 62, j = q - r * 62, grow = row0 + r;
        float4 v;
        if (j < 16) v = reinterpret_cast<const float4*>(user_emb + (size_t)user[grow] * 64)[j];
        else if (j < 32) v = reinterpret_cast<const float4*>(item_emb + (size_t)item[grow] * 64)[j - 16];
        else if (j < 37) v = reinterpret_cast<const float4*>(genre + (size_t)grow * 20)[j - 32];
        else v = reinterpret_cast<const float4*>(tag + (size_t)grow * 100)[j - 37];
        *reinterpret_cast<float4*>(sA + r * 248 + j * 4) = v;
    }
    for (int q = tid; q < TB * 16; q += NTHR) {
        int r = q >> 4, j = q & 15, grow = row0 + r;
        float4 a = reinterpret_cast<const float4*>(wide_W + (size_t)user[grow] * 64)[j];
        float4 b = reinterpret_cast<const float4*>(wide_W + (size_t)(NU + item[grow]) * 64)[j];
        float4 c = reinterpret_cast<const float4*>(wide_b)[j];
        *reinterpret_cast<float4*>(sC + r * 64 + j * 4) =
            make_float4(a.x + b.x + c.x, a.y + b.y + c.y, a.z + b.z + c.z, a.w + b.w + c.w);
    }
    __syncthreads();
    {
        const int cg = tid & 63, r0 = (tid >> 6) * 8;
        float4 acc[8];
        #pragma unroll
        for (int r = 0; r < 8; ++r) acc[r] = make_float4(0.f, 0.f, 0.f, 0.f);
        for (int k = 0; k < 248; k += 4) {
            const float4* wp = reinterpret_cast<const float4*>(W0 + (size_t)k * 256) + cg;
            float4 w0 = wp[0], w1 = wp[64], w2 = wp[128], w3 = wp[192];
            #pragma unroll
            for (int r = 0; r < 8; ++r) {
                float4 xv = *reinterpret_cast<const float4*>(sA + (r0 + r) * 248 + k);
                fma4(acc[r], xv.x, w0); fma4(acc[r], xv.y, w1);
                fma4(acc[r], xv.z, w2); fma4(acc[r], xv.w, w3);
            }
        }
        float4 bb = reinterpret_cast<const float4*>(b0)[cg];
        #pragma unroll
        for (int r = 0; r < 8; ++r)
            *reinterpret_cast<float4*>(sB + (r0 + r) * 256 + cg * 4) = relu4(add4(acc[r], bb));
    }
    __syncthreads();
    {
        const int cg = tid & 31, r0 = (tid >> 5) * 4;
        float4 acc[4];
        #pragma unroll
        for (int r = 0; r < 4; ++r) acc[r] = make_float4(0.f, 0.f, 0.f, 0.f);
        for (int k = 0; k < 256; k += 4) {
            const float4* wp = reinterpret_cast<const float4*>(W1 + (size_t)k * 128) + cg;
            float4 w0 = wp[0], w1 = wp[32], w2 = wp[64], w3 = wp[96];
            #pragma unroll
            for (int r = 0; r < 4; ++r) {
                float4 xv = *reinterpret_cast<const float4*>(sB + (r0 + r) * 256 + k);
                fma4(acc[r], xv.x, w0); fma4(acc[r], xv.y, w1);
                fma4(acc[r], xv.z, w2); fma4(acc[r], xv.w, w3);
            }
        }
        float4 bb = reinterpret_cast<const float4*>(b1)[cg];
        #pragma unroll
        for (int r = 0; r < 4; ++r)
            *reinterpret_cast<float4*>(sA + (r0 + r) * 128 + cg * 4) = relu4(add4(acc[r], bb));
    }
    __syncthreads();
    {
        const int cg = tid & 15, r0 = (tid >> 4) * 2;
        float4 acc[2];
        acc[0] = make_float4(0.f, 0.f, 0.f, 0.f); acc[1] = acc[0];
        for (int k = 0; k < 128; k += 4) {
            const float4* wp = reinterpret_cast<const float4*>(W2 + (size_t)k * 64) + cg;
            float4 w0 = wp[0], w1 = wp[16], w2 = wp[32], w3 = wp[48];
            #pragma unroll
            for (int r = 0; r < 2; ++r) {
                float4 xv = *reinterpret_cast<const float4*>(sA + (r0 + r) * 128 + k);
                fma4(acc[r], xv.x, w0); fma4(acc[r], xv.y, w1);
                fma4(acc[r], xv.z, w2); fma4(acc[r], xv.w, w3);
            }
        }
        float4 bb = reinterpret_cast<const float4*>(b2)[cg];
        #pragma unroll
        for (int r = 0; r < 2; ++r)
            *reinterpret_cast<float4*>(sB + (r0 + r) * 64 + cg * 4) = relu4(add4(acc[r], bb));
    }
    __syncthreads();
    if (tid < TB * 5) {
        int r = tid / 5, c = tid - r * 5;
        float acc = fb[c];
        for (int k = 0; k < 64; ++k) acc = fmaf(sB[r * 64 + k], fW[k * 5 + c], acc);
        for (int k = 0; k < 64; ++k) acc = fmaf(sC[r * 64 + k], fW[(64 + k) * 5 + c], acc);
        out[(size_t)(row0 + r) * 5 + c] = acc;
    }
}

extern "C" void kernel_launch(void* const* d_in, const int* in_sizes, int n_in,
                              void* d_out, int out_size, void* d_ws, size_t ws_size,
                              hipStream_t stream) {
    const int* user = (const int*)d_in[0];
    const int* item = (const int*)d_in[1];
    const float* genre = (const float*)d_in[2];
    const float* tag = (const float*)d_in[3];
    const float* wide_W = (const float*)d_in[4];
    const float* wide_b = (const float*)d_in[5];
    const float* user_emb = (const float*)d_in[6];
    const float* item_emb = (const float*)d_in[7];
    const float* W0 = (const float*)d_in[8];
    const float* b0 = (const float*)d_in[9];
    const float* W1 = (const float*)d_in[10];
    const float* b1 = (const float*)d_in[11];
    const float* W2 = (const float*)d_in[12];
    const float* b2 = (const float*)d_in[13];
    const float* fW = (const float*)d_in[14];
    const float* fb = (const float*)d_in[15];
    float* out = (float*)d_out;

    if (ws_size >= (size_t)WSREQ) {
        hipLaunchKernelGGL(prep_weights, dim3(52), dim3(256), 0, stream,
                           W0, W1, W2, (unsigned short*)d_ws);
        hipLaunchKernelGGL(wd_mfma, dim3(BATCH / TBR), dim3(MT), 0, stream,
                           user, item, genre, tag, wide_W, wide_b, user_emb, item_emb,
                           b0, b1, b2, fW, fb, (const unsigned short*)d_ws, out);
    } else {
        hipLaunchKernelGGL(wd_fused, dim3(BATCH / TB), dim3(NTHR), 0, stream,
                           user, item, genre, tag, wide_W, wide_b, user_emb, item_emb,
                           W0, b0, W1, b1, W2, b2, fW, fb, out);
    }
}

// Round 7
// 30.383 us; speedup vs baseline: 1.3124x; 1.0156x over previous
//
#include <hip/hip_runtime.h>

#define BATCH 16384
#define NU 1000000
#define TBR 64           // rows per block (mfma kernel)
#define MT 512           // threads (mfma kernel), 8 waves
#define WSOFF0 0         // W0t [256][256] bf16
#define WSOFF1 65536     // W1t [128][256] bf16
#define WSOFF2 98304     // W2t [64][128]  bf16
#define WSREQ  212992    // bytes of ws needed

typedef __attribute__((ext_vector_type(8))) short short8;
typedef __attribute__((ext_vector_type(4))) short short4v;
typedef __attribute__((ext_vector_type(4))) float f32x4;

__device__ __forceinline__ unsigned short f32_bf16(float f) {
    unsigned int u = __float_as_uint(f);
    u += 0x7FFF + ((u >> 16) & 1);   // RTNE
    return (unsigned short)(u >> 16);
}
__device__ __forceinline__ float bf16_f32(unsigned short h) {
    return __uint_as_float(((unsigned int)h) << 16);
}

// XOR swizzle: 16B granule spread by row (bank-conflict-free ds_read_b128).
__device__ __forceinline__ int swz(int row, int byteInRow, int rowStrideB) {
    return row * rowStrideB + (byteInRow ^ ((row & 7) << 4));
}

__device__ __forceinline__ short8 cvt8(float4 a, float4 b) {
    short8 s;
    s[0] = (short)f32_bf16(a.x); s[1] = (short)f32_bf16(a.y);
    s[2] = (short)f32_bf16(a.z); s[3] = (short)f32_bf16(a.w);
    s[4] = (short)f32_bf16(b.x); s[5] = (short)f32_bf16(b.y);
    s[6] = (short)f32_bf16(b.z); s[7] = (short)f32_bf16(b.w);
    return s;
}

// ---- Pre-pass: transpose + bf16-convert weights into ws (Wt[n][k]) ----
__global__ void prep_weights(const float* __restrict__ W0, const float* __restrict__ W1,
                             const float* __restrict__ W2, unsigned short* __restrict__ ws)
{
    __shared__ float t[32 * 65];
    int b = blockIdx.x;
    const float* src; unsigned short* dst; int K, N, K2, k0, n0;
    if (b < 32)      { src = W0; dst = ws + WSOFF0; K = 248; N = 256; K2 = 256; k0 = (b >> 2) * 32; n0 = (b & 3) * 64; }
    else if (b < 48) { int i = b - 32; src = W1; dst = ws + WSOFF1; K = 256; N = 128; K2 = 256; k0 = (i >> 1) * 32; n0 = (i & 1) * 64; }
    else             { int i = b - 48; src = W2; dst = ws + WSOFF2; K = 128; N = 64;  K2 = 128; k0 = i * 32; n0 = 0; }

    int tid = threadIdx.x;
    for (int q = tid; q < 32 * 16; q += 256) {
        int k = q >> 4, nq = q & 15;
        float4 v = make_float4(0.f, 0.f, 0.f, 0.f);
        if (k0 + k < K) v = *(const float4*)(src + (size_t)(k0 + k) * N + n0 + nq * 4);
        t[k * 65 + nq * 4 + 0] = v.x;
        t[k * 65 + nq * 4 + 1] = v.y;
        t[k * 65 + nq * 4 + 2] = v.z;
        t[k * 65 + nq * 4 + 3] = v.w;
    }
    __syncthreads();
    {
        int q = tid;
        int n = q >> 2, kg = q & 3;
        short8 o;
        #pragma unroll
        for (int i = 0; i < 8; ++i) o[i] = (short)f32_bf16(t[(kg * 8 + i) * 65 + n]);
        *(short8*)(dst + (size_t)(n0 + n) * K2 + k0 + kg * 8) = o;
    }
}

// ---- Main fused MFMA kernel: 256 blocks x 512 thr, 64 rows/block ----
// 2-half software pipeline: gather | L0(A) | L0(B)+L1(A) | L1(B)+L2(A) | L2(B) | final
__global__ __launch_bounds__(MT, 1) void wd_mfma(
        const int* __restrict__ user, const int* __restrict__ item,
        const float* __restrict__ genre, const float* __restrict__ tag,
        const float* __restrict__ wide_W, const float* __restrict__ wide_b,
        const float* __restrict__ user_emb, const float* __restrict__ item_emb,
        const float* __restrict__ b0, const float* __restrict__ b1,
        const float* __restrict__ b2,
        const float* __restrict__ fW, const float* __restrict__ fb,
        const unsigned short* __restrict__ ws, float* __restrict__ out)
{
    __shared__ unsigned short sX[TBR * 256];   // x tile bf16 (swizzled, 512B rows)
    __shared__ unsigned short sH0[TBR * 256];  // h0 bf16 (swizzled, 512B rows)
    __shared__ unsigned short sH1[TBR * 128];  // h1 bf16 (swizzled, 256B rows)
    __shared__ unsigned short sH2[TBR * 72];   // h2 bf16 (stride 72)
    __shared__ unsigned short sWide[TBR * 72]; // wide bf16 (stride 72)
    __shared__ float sFW[640];                 // fW fp32

    const int tid = threadIdx.x;
    const int row0 = blockIdx.x * TBR;
    const unsigned short* w0t = ws + WSOFF0;
    const unsigned short* w1t = ws + WSOFF1;
    const unsigned short* w2t = ws + WSOFF2;

    const int wid = tid >> 6;
    const int lane = tid & 63;
    const int lr = lane & 15;     // row/col within 16-tile
    const int lh = lane >> 4;     // k-chunk 0..3

    // ---- Prefetch ALL weight B-fragments + biases into registers (pre-barrier) ----
    const int cb0 = wid * 32;          // L0 col strip
    const int cb1 = wid * 16;          // L1 col strip
    const int cb2 = (wid & 3) * 16;    // L2 col strip
    const int rq2 = (wid >> 2) * 16;   // L2 row-quarter within a 32-row half
    short8 B0[2][8];
    #pragma unroll
    for (int t = 0; t < 2; ++t)
        #pragma unroll
        for (int kc = 0; kc < 8; ++kc)
            B0[t][kc] = *(const short8*)(w0t + (size_t)(cb0 + t * 16 + lr) * 256 + kc * 32 + lh * 8);
    short8 B1[8];
    #pragma unroll
    for (int kc = 0; kc < 8; ++kc)
        B1[kc] = *(const short8*)(w1t + (size_t)(cb1 + lr) * 256 + kc * 32 + lh * 8);
    short8 B2f[4];
    #pragma unroll
    for (int kc = 0; kc < 4; ++kc)
        B2f[kc] = *(const short8*)(w2t + (size_t)(cb2 + lr) * 128 + kc * 32 + lh * 8);
    float rb0[2];
    rb0[0] = b0[cb0 + lr]; rb0[1] = b0[cb0 + 16 + lr];
    float rb1 = b1[cb1 + lr];
    float rb2 = b2[cb2 + lr];

    // ---- Stage x (bf16, swizzled) + wide path together: all gathers overlap ----
    #pragma unroll
    for (int it = 0; it < 6; ++it) {
        int q = tid + it * MT;
        if (it < 4) {
            int r = q >> 5, j = q & 31;
            int grow = row0 + r;
            float4 va = make_float4(0.f, 0.f, 0.f, 0.f);
            float4 vb = va;
            if (j < 8) {
                const float4* p = (const float4*)(user_emb + (size_t)user[grow] * 64);
                va = p[j * 2]; vb = p[j * 2 + 1];
            } else if (j < 16) {
                const float4* p = (const float4*)(item_emb + (size_t)item[grow] * 64);
                va = p[(j - 8) * 2]; vb = p[(j - 8) * 2 + 1];
            } else if (j == 16) {
                const float4* p = (const float4*)(genre + (size_t)grow * 20);
                va = p[0]; vb = p[1];
            } else if (j == 17) {
                const float4* p = (const float4*)(genre + (size_t)grow * 20);
                va = p[2]; vb = p[3];
            } else if (j == 18) {
                va = *(const float4*)(genre + (size_t)grow * 20 + 16);
                vb = *(const float4*)(tag + (size_t)grow * 100);
            } else if (j < 31) {
                const float4* p = (const float4*)(tag + (size_t)grow * 100 + 4);
                int jj = j - 19;
                va = p[jj * 2]; vb = p[jj * 2 + 1];
            } // j == 31: zero pad (k 248..255)
            *(short8*)((char*)sX + swz(r, j * 16, 512)) = cvt8(va, vb);
        } else {
            int p = q - 4 * MT;
            int r = p >> 4, j = p & 15;
            int grow = row0 + r;
            float4 a = ((const float4*)(wide_W + (size_t)user[grow] * 64))[j];
            float4 b = ((const float4*)(wide_W + (size_t)(NU + item[grow]) * 64))[j];
            float4 c = ((const float4*)wide_b)[j];
            short4v o;
            o[0] = (short)f32_bf16(a.x + b.x + c.x);
            o[1] = (short)f32_bf16(a.y + b.y + c.y);
            o[2] = (short)f32_bf16(a.z + b.z + c.z);
            o[3] = (short)f32_bf16(a.w + b.w + c.w);
            *(short4v*)(sWide + r * 72 + j * 4) = o;
        }
    }
    if (tid < 160) {
        ((float4*)sFW)[tid] = ((const float4*)fW)[tid];
    }

    // ---- Per-half layer bodies (h = 0: rows 0-31, h = 1: rows 32-63) ----
    auto do_L0 = [&](int h) {
        const int rb = h * 32;
        f32x4 acc[2][2];
        #pragma unroll
        for (int rt = 0; rt < 2; ++rt)
            #pragma unroll
            for (int t = 0; t < 2; ++t) acc[rt][t] = (f32x4)(0.f);
        #pragma unroll
        for (int kc = 0; kc < 8; ++kc) {
            const int kb = kc * 32 + lh * 8;
            short8 a[2];
            #pragma unroll
            for (int rt = 0; rt < 2; ++rt)
                a[rt] = *(const short8*)((const char*)sX + swz(rb + rt * 16 + lr, kb * 2, 512));
            #pragma unroll
            for (int t = 0; t < 2; ++t)
                #pragma unroll
                for (int rt = 0; rt < 2; ++rt)
                    acc[rt][t] = __builtin_amdgcn_mfma_f32_16x16x32_bf16(a[rt], B0[t][kc], acc[rt][t], 0, 0, 0);
        }
        #pragma unroll
        for (int t = 0; t < 2; ++t)
            #pragma unroll
            for (int rt = 0; rt < 2; ++rt)
                #pragma unroll
                for (int jj = 0; jj < 4; ++jj) {
                    int row = rb + rt * 16 + lh * 4 + jj;
                    float v = fmaxf(acc[rt][t][jj] + rb0[t], 0.f);
                    *(unsigned short*)((char*)sH0 + swz(row, (cb0 + t * 16 + lr) * 2, 512)) = f32_bf16(v);
                }
    };

    auto do_L1 = [&](int h) {
        const int rb = h * 32;
        f32x4 acc[2];
        acc[0] = (f32x4)(0.f); acc[1] = (f32x4)(0.f);
        #pragma unroll
        for (int kc = 0; kc < 8; ++kc) {
            const int kb = kc * 32 + lh * 8;
            short8 a[2];
            #pragma unroll
            for (int rt = 0; rt < 2; ++rt)
                a[rt] = *(const short8*)((const char*)sH0 + swz(rb + rt * 16 + lr, kb * 2, 512));
            #pragma unroll
            for (int rt = 0; rt < 2; ++rt)
                acc[rt] = __builtin_amdgcn_mfma_f32_16x16x32_bf16(a[rt], B1[kc], acc[rt], 0, 0, 0);
        }
        #pragma unroll
        for (int rt = 0; rt < 2; ++rt)
            #pragma unroll
            for (int jj = 0; jj < 4; ++jj) {
                int row = rb + rt * 16 + lh * 4 + jj;
                float v = fmaxf(acc[rt][jj] + rb1, 0.f);
                *(unsigned short*)((char*)sH1 + swz(row, (cb1 + lr) * 2, 256)) = f32_bf16(v);
            }
    };

    auto do_L2 = [&](int h) {
        const int rb = h * 32 + rq2;
        f32x4 acc = (f32x4)(0.f);
        #pragma unroll
        for (int kc = 0; kc < 4; ++kc) {
            const int kb = kc * 32 + lh * 8;
            short8 a = *(const short8*)((const char*)sH1 + swz(rb + lr, kb * 2, 256));
            acc = __builtin_amdgcn_mfma_f32_16x16x32_bf16(a, B2f[kc], acc, 0, 0, 0);
        }
        #pragma unroll
        for (int jj = 0; jj < 4; ++jj) {
            int row = rb + lh * 4 + jj;
            sH2[row * 72 + cb2 + lr] = f32_bf16(fmaxf(acc[jj] + rb2, 0.f));
        }
    };

    // ---- Pipelined phase schedule (5 barriers, two streams per interval) ----
    __syncthreads();
    do_L0(0);
    __syncthreads();
    do_L0(1);
    do_L1(0);
    __syncthreads();
    do_L1(1);
    do_L2(0);
    __syncthreads();
    do_L2(1);
    __syncthreads();

    // ---- Final: [h2 | wide] @ fW + fb (fp32 VALU, LDS reads) ----
    if (tid < TBR * 5) {
        int r = tid / 5, c = tid - r * 5;
        float acc = fb[c];
        #pragma unroll
        for (int kq = 0; kq < 8; ++kq) {
            short8 h = *(const short8*)(sH2 + r * 72 + kq * 8);
            #pragma unroll
            for (int i = 0; i < 8; ++i)
                acc = fmaf(bf16_f32((unsigned short)h[i]), sFW[(kq * 8 + i) * 5 + c], acc);
        }
        #pragma unroll
        for (int kq = 0; kq < 8; ++kq) {
            short8 h = *(const short8*)(sWide + r * 72 + kq * 8);
            #pragma unroll
            for (int i = 0; i < 8; ++i)
                acc = fmaf(bf16_f32((unsigned short)h[i]), sFW[(64 + kq * 8 + i) * 5 + c], acc);
        }
        out[(size_t)(row0 + r) * 5 + c] = acc;
    }
}

// ================= fp32 fallback (used if ws too small) =================
#define NTHR 256
#define TB 32

__device__ __forceinline__ void fma4(float4& a, float s, const float4& w) {
    a.x = fmaf(s, w.x, a.x); a.y = fmaf(s, w.y, a.y);
    a.z = fmaf(s, w.z, a.z); a.w = fmaf(s, w.w, a.w);
}
__device__ __forceinline__ float4 add4(const float4& a, const float4& b) {
    return make_float4(a.x + b.x, a.y + b.y, a.z + b.z, a.w + b.w);
}
__device__ __forceinline__ float4 relu4(const float4& a) {
    return make_float4(fmaxf(a.x, 0.f), fmaxf(a.y, 0.f), fmaxf(a.z, 0.f), fmaxf(a.w, 0.f));
}

__global__ void wd_fused(const int* __restrict__ user, const int* __restrict__ item,
                         const float* __restrict__ genre, const float* __restrict__ tag,
                         const float* __restrict__ wide_W, const float* __restrict__ wide_b,
                         const float* __restrict__ user_emb, const float* __restrict__ item_emb,
                         const float* __restrict__ W0, const float* __restrict__ b0,
                         const float* __restrict__ W1, const float* __restrict__ b1,
                         const float* __restrict__ W2, const float* __restrict__ b2,
                         const float* __restrict__ fW, const float* __restrict__ fb,
                         float* __restrict__ out)
{
    __shared__ float sA[TB * 248];
    __shared__ float sB[TB * 256];
    __shared__ float sC[TB * 64];

    const int tid = threadIdx.x;
    const int row0 = blockIdx.x * TB;

    for (int q = tid; q < TB * 62; q += NTHR) {
        int r = q / 62, j = q - r * 62, grow = row0 + r;
        float4 v;
        if (j < 16) v = reinterpret_cast<const float4*>(user_emb + (size_t)user[grow] * 64)[j];
        else if (j < 32) v = reinterpret_cast<const float4*>(item_emb + (size_t)item[grow] * 64)[j - 16];
        else if (j < 37) v = reinterpret_cast<const float4*>(genre + (size_t)grow * 20)[j - 32];
        else v = reinterpret_cast<const float4*>(tag + (size_t)grow * 100)[j - 37];
        *reinterpret_cast<float4*>(sA + r * 248 + j * 4) = v;
    }
    for (int q = tid; q < TB * 16; q += NTHR) {
        int r = q >> 4, j = q & 15, grow = row0 + r;
        float4 a = reinterpret_cast<const float4*>(wide_W + (size_t)user[grow] * 64)[j];
        float4 b = reinterpret_cast<const float4*>(wide_W + (size_t)(NU + item[grow]) * 64)[j];
        float4 c = reinterpret_cast<const float4*>(wide_b)[j];
        *reinterpret_cast<float4*>(sC + r * 64 + j * 4) =
            make_float4(a.x + b.x + c.x, a.y + b.y + c.y, a.z + b.z + c.z, a.w + b.w + c.w);
    }
    __syncthreads();
    {
        const int cg = tid & 63, r0 = (tid >> 6) * 8;
        float4 acc[8];
        #pragma unroll
        for (int r = 0; r < 8; ++r) acc[r] = make_float4(0.f, 0.f, 0.f, 0.f);
        for (int k = 0; k < 248; k += 4) {
            const float4* wp = reinterpret_cast<const float4*>(W0 + (size_t)k * 256) + cg;
            float4 w0 = wp[0], w1 = wp[64], w2 = wp[128], w3 = wp[192];
            #pragma unroll
            for (int r = 0; r < 8; ++r) {
                float4 xv = *reinterpret_cast<const float4*>(sA + (r0 + r) * 248 + k);
                fma4(acc[r], xv.x, w0); fma4(acc[r], xv.y, w1);
                fma4(acc[r], xv.z, w2); fma4(acc[r], xv.w, w3);
            }
        }
        float4 bb = reinterpret_cast<const float4*>(b0)[cg];
        #pragma unroll
        for (int r = 0; r < 8; ++r)
            *reinterpret_cast<float4*>(sB + (r0 + r) * 256 + cg * 4) = relu4(add4(acc[r], bb));
    }
    __syncthreads();
    {
        const int cg = tid & 31, r0 = (tid >> 5) * 4;
        float4 acc[4];
        #pragma unroll
        for (int r = 0; r < 4; ++r) acc[r] = make_float4(0.f, 0.f, 0.f, 0.f);
        for (int k = 0; k < 256; k += 4) {
            const float4* wp = reinterpret_cast<const float4*>(W1 + (size_t)k * 128) + cg;
            float4 w0 = wp[0], w1 = wp[32], w2 = wp[64], w3 = wp[96];
            #pragma unroll
            for (int r = 0; r < 4; ++r) {
                float4 xv = *reinterpret_cast<const float4*>(sB + (r0 + r) * 256 + k);
                fma4(acc[r], xv.x, w0); fma4(acc[r], xv.y, w1);
                fma4(acc[r], xv.z, w2); fma4(acc[r], xv.w, w3);
            }
        }
        float4 bb = reinterpret_cast<const float4*>(b1)[cg];
        #pragma unroll
        for (int r = 0; r < 4; ++r)
            *reinterpret_cast<float4*>(sA + (r0 + r) * 128 + cg * 4) = relu4(add4(acc[r], bb));
    }
    __syncthreads();
    {
        const int cg = tid & 15, r0 = (tid >> 4) * 2;
        float4 acc[2];
        acc[0] = make_float4(0.f, 0.f, 0.f, 0.f); acc[1] = acc[0];
        for (int k = 0; k < 128; k += 4) {
            const float4* wp = reinterpret_cast<const float4*>(W2 + (size_t)k * 64) + cg;
            float4 w0 = wp[0], w1 = wp[16], w2 = wp[32], w3 = wp[48];
            #pragma unroll
            for (int r = 0; r < 2; ++r) {
                float4 xv = *reinterpret_cast<const float4*>(sA + (r0 + r) * 128 + k);
                fma4(acc[r], xv.x, w0); fma4(acc[r], xv.y, w1);
                fma4(acc[r], xv.z, w2); fma4(acc[r], xv.w, w3);
            }
        }
        float4 bb = reinterpret_cast<const float4*>(b2)[cg];
        #pragma unroll
        for (int r = 0; r < 2; ++r)
            *reinterpret_cast<float4*>(sB + (r0 + r) * 64 + cg * 4) = relu4(add4(acc[r], bb));
    }
    __syncthreads();
    if (tid < TB * 5) {
        int r = tid / 5, c = tid - r * 5;
        float acc = fb[c];
        for (int k = 0; k < 64; ++k) acc = fmaf(sB[r * 64 + k], fW[k * 5 + c], acc);
        for (int k = 0; k < 64; ++k) acc = fmaf(sC[r * 64 + k], fW[(64 + k) * 5 + c], acc);
        out[(size_t)(row0 + r) * 5 + c] = acc;
    }
}

extern "C" void kernel_launch(void* const* d_in, const int* in_sizes, int n_in,
                              void* d_out, int out_size, void* d_ws, size_t ws_size,
                              hipStream_t stream) {
    const int* user = (const int*)d_in[0];
    const int* item = (const int*)d_in[1];
    const float* genre = (const float*)d_in[2];
    const float* tag = (const float*)d_in[3];
    const float* wide_W = (const float*)d_in[4];
    const float* wide_b = (const float*)d_in[5];
    const float* user_emb = (const float*)d_in[6];
    const float* item_emb = (const float*)d_in[7];
    const float* W0 = (const float*)d_in[8];
    const float* b0 = (const float*)d_in[9];
    const float* W1 = (const float*)d_in[10];
    const float* b1 = (const float*)d_in[11];
    const float* W2 = (const float*)d_in[12];
    const float* b2 = (const float*)d_in[13];
    const float* fW = (const float*)d_in[14];
    const float* fb = (const float*)d_in[15];
    float* out = (float*)d_out;

    if (ws_size >= (size_t)WSREQ) {
        hipLaunchKernelGGL(prep_weights, dim3(52), dim3(256), 0, stream,
                           W0, W1, W2, (unsigned short*)d_ws);
        hipLaunchKernelGGL(wd_mfma, dim3(BATCH / TBR), dim3(MT), 0, stream,
                           user, item, genre, tag, wide_W, wide_b, user_emb, item_emb,
                           b0, b1, b2, fW, fb, (const unsigned short*)d_ws, out);
    } else {
        hipLaunchKernelGGL(wd_fused, dim3(BATCH / TB), dim3(NTHR), 0, stream,
                           user, item, genre, tag, wide_W, wide_b, user_emb, item_emb,
                           W0, b0, W1, b1, W2, b2, fW, fb, out);
    }
}